// Round 13
// baseline (2153.499 us; speedup 1.0000x reference)
//
#include <hip/hip_runtime.h>
#include <math.h>

#define Bb 16
#define Ls 8192
#define Dm 128
#define NBK 6
#define Nst 32
#define NCl 16
#define Em 256
#define LC 128
#define NCH 64
#define BL (Bb*Ls)

typedef __attribute__((ext_vector_type(8))) short bfrag;   // 8 bf16 (4 VGPRs)
typedef __attribute__((ext_vector_type(4))) float f32x4;

// fast gelu (tanh-approx form, via exp2/rcp; branch-free)
__device__ __forceinline__ float geluf(float x) {
    float t = x * x;
    float g = x * fmaf(0.102952207f, t, 2.30234547f);   // 2u*log2(e)
    float e = exp2f(-g);
    return x * __builtin_amdgcn_rcpf(1.f + e);
}
__device__ __forceinline__ float sigmf(float x) {
    return __builtin_amdgcn_rcpf(1.f + exp2f(-1.44269504f * x));
}

__device__ __forceinline__ unsigned short bf16r(float x) {
    unsigned u = __float_as_uint(x);
    return (unsigned short)((u + 0x7FFFu + ((u >> 16) & 1u)) >> 16);
}
__device__ __forceinline__ void split2(float x, unsigned short& h, unsigned short& l) {
    h = bf16r(x);
    float hf = __uint_as_float(((unsigned)h) << 16);
    l = bf16r(x - hf);
}

// ---------------- conv: h[b,l,d] (token-major) ----------------
__global__ void s4e_conv(const float* __restrict__ x, const float* __restrict__ cw,
                         const float* __restrict__ cb, float* __restrict__ h) {
    int tid = blockIdx.x * 256 + threadIdx.x;     // B*L*32
    int d4 = tid & 31;
    int t = tid >> 5;
    int l = t & (Ls - 1);
    int b = t >> 13;
    const float* xb = x + (size_t)b * Ls;
    float xs[5];
#pragma unroll
    for (int k = 0; k < 5; ++k) {
        int p = l + k - 2;
        xs[k] = (p >= 0 && p < Ls) ? xb[p] : 0.f;
    }
    float4 acc;
    float* ap = &acc.x;
#pragma unroll
    for (int j = 0; j < 4; ++j) {
        int d = d4 * 4 + j;
        float a = cb[d];
#pragma unroll
        for (int k = 0; k < 5; ++k) a = fmaf(cw[d * 5 + k], xs[k], a);
        ap[j] = a;
    }
    *(float4*)&h[(size_t)t * Dm + d4 * 4] = acc;
}

// ---------------- LN stats: per-token mu, rs ----------------
__global__ void s4e_lnstat(const float* __restrict__ h, float2* __restrict__ stats) {
    int tid = threadIdx.x;
    int t = blockIdx.x * 64 + (tid >> 2);
    int sub = tid & 3;
    const float* hp = h + (size_t)t * Dm + sub * 32;
    float s = 0.f, q = 0.f;
#pragma unroll
    for (int i = 0; i < 8; ++i) {
        float4 v = *(const float4*)(hp + i * 4);
        s += v.x + v.y + v.z + v.w;
        q += v.x * v.x + v.y * v.y + v.z * v.z + v.w * v.w;
    }
    s += __shfl_xor(s, 1); s += __shfl_xor(s, 2);
    q += __shfl_xor(q, 1); q += __shfl_xor(q, 2);
    float mu = s * (1.f / Dm);
    float rs = rsqrtf(q * (1.f / Dm) - mu * mu + 1e-5f);
    if (sub == 0) stats[t] = make_float2(mu, rs);
}

// ---------------- S4 params for ALL layers: [n][d], wp = w^LC, Cc pre-doubled ----------------
__global__ void s4e_setup6(const float* __restrict__ log_dt, const float* __restrict__ lAr,
                           const float* __restrict__ Aim, const float* __restrict__ Cre,
                           const float* __restrict__ Cim, float2* __restrict__ wv6,
                           float2* __restrict__ wp6, float2* __restrict__ Cc6) {
    int i = blockIdx.x;          // layer
    int d = threadIdx.x;
    const float* ld  = log_dt + i * Dm;
    const float* la  = lAr + i * Dm * Nst;
    const float* ai  = Aim + i * Dm * Nst;
    const float* cre = Cre + i * Dm * Nst;
    const float* cim = Cim + i * Dm * Nst;
    float2* wv = wv6 + i * (Nst * Dm);
    float2* wp = wp6 + i * (Nst * Dm);
    float2* Cc = Cc6 + i * (Nst * Dm);
    float dt = expf(ld[d]);
    for (int n = 0; n < Nst; ++n) {
        int id = d * Nst + n;
        float Ar = -expf(la[id]);
        float Ai = ai[id];
        float xr = dt * Ar, xi = dt * Ai;
        float er = expf(xr);
        float wr = er * cosf(xi), wi = er * sinf(xi);
        wv[n * Dm + d] = make_float2(wr, wi);
        float den = Ar * Ar + Ai * Ai;
        float inv = 1.f / den;
        float fr = ((wr - 1.f) * Ar + wi * Ai) * inv;
        float fi = (wi * Ar - (wr - 1.f) * Ai) * inv;
        Cc[n * Dm + d] = make_float2(2.f * (cre[id] * fr - cim[id] * fi),
                                     2.f * (cre[id] * fi + cim[id] * fr));
        float pr = wr, pi = wi;
#pragma unroll
        for (int sq = 0; sq < 7; ++sq) {     // w^128 = w^LC
            float nr = pr * pr - pi * pi;
            float ni = 2.f * pr * pi;
            pr = nr; pi = ni;
        }
        wp[n * Dm + d] = make_float2(pr, pi);
    }
}

// ---------------- weight split + MFMA-fragment pack, ALL layers ----------------
// packed[((rt*KT + kt)*64 + lane)*8 + j] = W[rt*16 + (lane&15)][kt*32 + (lane>>4)*8 + j]
__global__ void s4e_wsplit6(const float* __restrict__ ow, const float* __restrict__ w1,
                            const float* __restrict__ w2, unsigned short* __restrict__ base0) {
    int idx = blockIdx.x * 256 + threadIdx.x;   // 6 layers * 12288 groups
    int layer = idx / 12288;
    int r = idx - layer * 12288;
    int mat = r >> 12;
    int g = r & 4095;
    int lane = g & 63;
    int fid = g >> 6;
    int col = lane & 15, q = lane >> 4;
    unsigned short* base = base0 + layer * 196608;
    const float* src;
    unsigned short *dh, *dl_;
    int rt, kt, K;
    if (mat == 0)      { src = ow + layer * 32768; K = 128; dh = base;          dl_ = base + 32768;  rt = fid >> 2; kt = fid & 3; }
    else if (mat == 1) { src = w1 + layer * 32768; K = 128; dh = base + 65536;  dl_ = base + 98304;  rt = fid >> 2; kt = fid & 3; }
    else               { src = w2 + layer * 32768; K = 256; dh = base + 131072; dl_ = base + 163840; rt = fid >> 3; kt = fid & 7; }
    int row = rt * 16 + col;
    int k0 = kt * 32 + q * 8;
    const float* sp = src + row * K + k0;
    bfrag vh, vl;
#pragma unroll
    for (int j = 0; j < 8; ++j) {
        unsigned short hh, ll;
        split2(sp[j], hh, ll);
        vh[j] = (short)hh; vl[j] = (short)ll;
    }
    *(bfrag*)&dh[g * 8] = vh;
    *(bfrag*)&dl_[g * 8] = vl;
}

// ---------------- S1: end states, inline LN, 4-way mode split (8 modes/thread) ----------------
// block = 64-d half of one chunk; tid: dl=tid&15, m=(tid>>4)&3, dq=tid>>6
__global__ __launch_bounds__(256) void s4e_s1(const float* __restrict__ h,
        const float2* __restrict__ stats, const float* __restrict__ lnw,
        const float* __restrict__ lnb, const float2* __restrict__ wv,
        float2* __restrict__ send) {
    __shared__ float2 stl[LC];
    int tid = threadIdx.x;
    int blk = blockIdx.x;            // (b*NCH + c)*2 + half
    int half = blk & 1;
    int chunk = blk >> 1;
    int c = chunk & (NCH - 1);
    int b = chunk >> 6;
    int dl = tid & 15;
    int m  = (tid >> 4) & 3;
    int dq = tid >> 6;
    int d  = half * 64 + dq * 16 + dl;
    int n0 = m * 8;
    if (tid < LC) stl[tid] = stats[(size_t)b * Ls + c * LC + tid];
    float wr[8], wi[8], sr[8], si[8];
#pragma unroll
    for (int k = 0; k < 8; ++k) {
        float2 t = wv[(n0 + k) * Dm + d];
        wr[k] = t.x; wi[k] = t.y; sr[k] = 0.f; si[k] = 0.f;
    }
    float wd = lnw[d], bd = lnb[d];
    const float* hp = h + ((size_t)b * Ls + c * LC) * Dm + d;
    __syncthreads();
#pragma unroll 1
    for (int j = 0; j < LC; j += 4) {
        float hv[4];
#pragma unroll
        for (int u = 0; u < 4; ++u) hv[u] = hp[(size_t)(j + u) * Dm];
        float zv[4];
#pragma unroll
        for (int u = 0; u < 4; ++u) {
            float2 sj = stl[j + u];
            zv[u] = (hv[u] - sj.x) * sj.y * wd + bd;
        }
#pragma unroll
        for (int u = 0; u < 4; ++u) {
            float z = zv[u];
#pragma unroll
            for (int k = 0; k < 8; ++k) {
                float t = fmaf(-wi[k], si[k], z);
                float nr = fmaf(wr[k], sr[k], t);
                float ni = fmaf(wi[k], sr[k], wr[k] * si[k]);
                sr[k] = nr; si[k] = ni;
            }
        }
    }
    float2* o = send + ((size_t)(b * NCH + c) * Nst + n0) * Dm + d;
#pragma unroll
    for (int k = 0; k < 8; ++k) o[k * Dm] = make_float2(sr[k], si[k]);
}

// ---------------- S2: in-place cross-chunk prefix ----------------
__global__ void s4e_s2(const float2* __restrict__ wp, float2* __restrict__ s) {
    int tid = blockIdx.x * 256 + threadIdx.x;   // B*Nst*Dm = 65536
    int d = tid & 127;
    int n = (tid >> 7) & 31;
    int b = tid >> 12;
    float2 W = wp[n * Dm + d];
    float Sr = 0.f, Si = 0.f;
    size_t base = ((size_t)(b * NCH) * Nst + n) * Dm + d;
    size_t cs = (size_t)Nst * Dm;
    for (int c0 = 0; c0 < NCH; c0 += 8) {
        float2 E[8];
#pragma unroll
        for (int k = 0; k < 8; ++k) E[k] = s[base + (size_t)(c0 + k) * cs];
#pragma unroll
        for (int k = 0; k < 8; ++k) {
            float2 o = make_float2(Sr, Si);
            float nr = fmaf(W.x, Sr, fmaf(-W.y, Si, E[k].x));
            float ni = fmaf(W.x, Si, fmaf(W.y, Sr, E[k].y));
            Sr = nr; Si = ni;
            s[base + (size_t)(c0 + k) * cs] = o;
        }
    }
}

// ---------------- S3: re-scan, inline LN, 4-way mode split, act bf16 hi/lo ----------------
__global__ __launch_bounds__(256) void s4e_s3(const float* __restrict__ h,
        const float2* __restrict__ stats, const float* __restrict__ lnw,
        const float* __restrict__ lnb, const float2* __restrict__ wv,
        const float2* __restrict__ Cc, const float2* __restrict__ sinit,
        const float* __restrict__ Dsk,
        unsigned short* __restrict__ acth, unsigned short* __restrict__ actl) {
    __shared__ float2 stl[LC];
    int tid = threadIdx.x;
    int blk = blockIdx.x;
    int half = blk & 1;
    int chunk = blk >> 1;
    int c = chunk & (NCH - 1);
    int b = chunk >> 6;
    int dl = tid & 15;
    int m  = (tid >> 4) & 3;
    int dq = tid >> 6;
    int d  = half * 64 + dq * 16 + dl;
    int n0 = m * 8;
    if (tid < LC) stl[tid] = stats[(size_t)b * Ls + c * LC + tid];
    float wr[8], wi[8], cr[8], ci[8], sr[8], si[8];
    const float2* s0 = sinit + ((size_t)(b * NCH + c) * Nst + n0) * Dm + d;
#pragma unroll
    for (int k = 0; k < 8; ++k) {
        float2 t = wv[(n0 + k) * Dm + d];  wr[k] = t.x; wi[k] = t.y;
        float2 cc = Cc[(n0 + k) * Dm + d]; cr[k] = cc.x; ci[k] = cc.y;
        float2 ss = s0[k * Dm];            sr[k] = ss.x; si[k] = ss.y;
    }
    float wd = lnw[d], bd = lnb[d];
    float Dv = Dsk[d];
    size_t ib = ((size_t)b * Ls + c * LC) * Dm + d;
    __syncthreads();
#pragma unroll 1
    for (int j = 0; j < LC; j += 4) {
        float hv[4];
#pragma unroll
        for (int u = 0; u < 4; ++u) hv[u] = h[ib + (size_t)(j + u) * Dm];
        float zv[4];
#pragma unroll
        for (int u = 0; u < 4; ++u) {
            float2 sj = stl[j + u];
            zv[u] = (hv[u] - sj.x) * sj.y * wd + bd;
        }
#pragma unroll
        for (int u = 0; u < 4; ++u) {
            float z = zv[u];
            float acc = 0.f;
#pragma unroll
            for (int k = 0; k < 8; ++k) {
                float t = fmaf(-wi[k], si[k], z);
                float nr = fmaf(wr[k], sr[k], t);
                float ni = fmaf(wi[k], sr[k], wr[k] * si[k]);
                sr[k] = nr; si[k] = ni;
                acc = fmaf(cr[k], nr, acc);
                acc = fmaf(-ci[k], ni, acc);
            }
            acc += __shfl_xor(acc, 16);   // combine m-bit0
            acc += __shfl_xor(acc, 32);   // combine m-bit1
            if (m == 0) {
                float av = geluf(fmaf(Dv, z, acc));
                unsigned short hh, ll;
                split2(av, hh, ll);
                acth[ib + (size_t)(j + u) * Dm] = hh;
                actl[ib + (size_t)(j + u) * Dm] = ll;
            }
        }
    }
}

// ---------------- outproj GEMM (bf16x3 MFMA, packed weights) + GLU ----------------
__global__ __launch_bounds__(256) void s4e_outproj(const unsigned short* __restrict__ acth,
        const unsigned short* __restrict__ actl, const unsigned short* __restrict__ wsp,
        const float* __restrict__ bias, float* __restrict__ h) {
    __shared__ __align__(16) unsigned short smem[8192];   // Ah 8K | Al 8K ; Rf aliases 16K
    unsigned short* Ah = smem;
    unsigned short* Al = smem + 4096;
    float* Rf = (float*)smem;
    const unsigned short* Whi = wsp;
    const unsigned short* Wlo = wsp + 32768;
    size_t l0 = (size_t)blockIdx.x * 32;
    int tid = threadIdx.x;
    {
        const unsigned short* gh = acth + l0 * Dm;
        const unsigned short* gl = actl + l0 * Dm;
        for (int i = tid * 8; i < 32 * 128; i += 2048) {
            int r = i >> 7;
            int di = i ^ ((r & 7) << 3);
            *(bfrag*)&Ah[di] = *(const bfrag*)&gh[i];
            *(bfrag*)&Al[di] = *(const bfrag*)&gl[i];
        }
    }
    __syncthreads();
    int w = tid >> 6, lane = tid & 63;
    int col = lane & 15, q = lane >> 4;
    f32x4 acc[2][4];
#pragma unroll
    for (int m = 0; m < 2; ++m)
#pragma unroll
        for (int nt = 0; nt < 4; ++nt) acc[m][nt] = (f32x4){0.f, 0.f, 0.f, 0.f};
#pragma unroll
    for (int ks = 0; ks < 4; ++ks) {
        int kb = ks * 32 + q * 8;
        int i0 = (col * 128 + kb) ^ ((col & 7) << 3);
        int i1 = ((16 + col) * 128 + kb) ^ ((col & 7) << 3);
        bfrag a0h = *(bfrag*)&Ah[i0], a0l = *(bfrag*)&Al[i0];
        bfrag a1h = *(bfrag*)&Ah[i1], a1l = *(bfrag*)&Al[i1];
#pragma unroll
        for (int nt = 0; nt < 4; ++nt) {
            int rt = (nt < 2) ? (w * 2 + nt) : (8 + w * 2 + (nt - 2));
            int off = ((rt * 4 + ks) * 64 + lane) * 8;
            bfrag bh = *(const bfrag*)&Whi[off];
            bfrag bl = *(const bfrag*)&Wlo[off];
            acc[0][nt] = __builtin_amdgcn_mfma_f32_16x16x32_bf16(a0h, bh, acc[0][nt], 0, 0, 0);
            acc[0][nt] = __builtin_amdgcn_mfma_f32_16x16x32_bf16(a0h, bl, acc[0][nt], 0, 0, 0);
            acc[0][nt] = __builtin_amdgcn_mfma_f32_16x16x32_bf16(a0l, bh, acc[0][nt], 0, 0, 0);
            acc[1][nt] = __builtin_amdgcn_mfma_f32_16x16x32_bf16(a1h, bh, acc[1][nt], 0, 0, 0);
            acc[1][nt] = __builtin_amdgcn_mfma_f32_16x16x32_bf16(a1h, bl, acc[1][nt], 0, 0, 0);
            acc[1][nt] = __builtin_amdgcn_mfma_f32_16x16x32_bf16(a1l, bh, acc[1][nt], 0, 0, 0);
        }
    }
    __syncthreads();   // all Ah/Al reads done before Rf overwrite
#pragma unroll
    for (int m = 0; m < 2; ++m)
#pragma unroll
        for (int nt = 0; nt < 2; ++nt) {
            int dout = w * 32 + nt * 16 + col;
            float ba = bias[dout], bg = bias[dout + 128];
#pragma unroll
            for (int r = 0; r < 4; ++r) {
                int l = m * 16 + q * 4 + r;
                float a = acc[m][nt][r] + ba;
                float g = acc[m][nt + 2][r] + bg;
                Rf[l * 128 + dout] = a * sigmf(g);
            }
        }
    __syncthreads();
    size_t gb = l0 * Dm + (size_t)tid * 16;
#pragma unroll
    for (int i = 0; i < 4; ++i) {
        float4 r = *(float4*)&Rf[tid * 16 + i * 4];
        float4 hv = *(float4*)&h[gb + i * 4];
        hv.x += r.x; hv.y += r.y; hv.z += r.z; hv.w += r.w;
        *(float4*)&h[gb + i * 4] = hv;
    }
}

// ---------------- fused LN + FF GEMM (bf16x3 MFMA, packed weights) ----------------
__global__ __launch_bounds__(256) void s4e_ffk(const float* __restrict__ lnw,
        const float* __restrict__ lnb, const unsigned short* __restrict__ wsp,
        const float* __restrict__ b1, const float* __restrict__ b2, float* __restrict__ h) {
    __shared__ __align__(16) unsigned short smem[24576]; // Zh 8K|Zl 8K|Eh 16K|El 16K (bytes)
    unsigned short* Zh = smem;
    unsigned short* Zl = smem + 4096;
    unsigned short* Eh = smem + 8192;
    unsigned short* El = smem + 16384;
    float* Rf = (float*)smem;                 // aliases Zh+Zl (16 KB)
    const unsigned short* W1h = wsp + 65536;
    const unsigned short* W1l = wsp + 98304;
    const unsigned short* W2h = wsp + 131072;
    const unsigned short* W2l = wsp + 163840;
    size_t l0 = (size_t)blockIdx.x * 32;
    int tid = threadIdx.x;
    // ---- fused LN
    float hf[16];
    float s = 0.f, qq = 0.f;
    {
        const float* hp = h + l0 * Dm + (size_t)tid * 16;
#pragma unroll
        for (int i = 0; i < 4; ++i) {
            float4 v = *(const float4*)(hp + i * 4);
            hf[i * 4 + 0] = v.x; hf[i * 4 + 1] = v.y;
            hf[i * 4 + 2] = v.z; hf[i * 4 + 3] = v.w;
            s += v.x + v.y + v.z + v.w;
            qq += v.x * v.x + v.y * v.y + v.z * v.z + v.w * v.w;
        }
    }
    s  += __shfl_xor(s, 1);  s += __shfl_xor(s, 2);  s += __shfl_xor(s, 4);
    qq += __shfl_xor(qq, 1); qq += __shfl_xor(qq, 2); qq += __shfl_xor(qq, 4);
    float mu = s * (1.f / Dm);
    float rs = rsqrtf(qq * (1.f / Dm) - mu * mu + 1e-5f);
    int tok = tid >> 3, dc = (tid & 7) * 16;
#pragma unroll
    for (int g = 0; g < 2; ++g) {
        bfrag vh, vl;
#pragma unroll
        for (int k = 0; k < 8; ++k) {
            int d = dc + g * 8 + k;
            float v = (hf[g * 8 + k] - mu) * rs * lnw[d] + lnb[d];
            unsigned short hh, ll;
            split2(v, hh, ll);
            vh[k] = (short)hh; vl[k] = (short)ll;
        }
        int idx = (tok * 128 + dc + g * 8) ^ ((tok & 7) << 3);
        *(bfrag*)&Zh[idx] = vh;
        *(bfrag*)&Zl[idx] = vl;
    }
    __syncthreads();
    int w = tid >> 6, lane = tid & 63;
    int col = lane & 15, q = lane >> 4;
    f32x4 acc[2][4];
#pragma unroll
    for (int m = 0; m < 2; ++m)
#pragma unroll
        for (int nt = 0; nt < 4; ++nt) acc[m][nt] = (f32x4){0.f, 0.f, 0.f, 0.f};
#pragma unroll
    for (int ks = 0; ks < 4; ++ks) {
        int kb = ks * 32 + q * 8;
        int i0 = (col * 128 + kb) ^ ((col & 7) << 3);
        int i1 = ((16 + col) * 128 + kb) ^ ((col & 7) << 3);
        bfrag a0h = *(bfrag*)&Zh[i0], a0l = *(bfrag*)&Zl[i0];
        bfrag a1h = *(bfrag*)&Zh[i1], a1l = *(bfrag*)&Zl[i1];
#pragma unroll
        for (int nt = 0; nt < 4; ++nt) {
            int rt = w * 4 + nt;
            int off = ((rt * 4 + ks) * 64 + lane) * 8;
            bfrag bh = *(const bfrag*)&W1h[off];
            bfrag bl = *(const bfrag*)&W1l[off];
            acc[0][nt] = __builtin_amdgcn_mfma_f32_16x16x32_bf16(a0h, bh, acc[0][nt], 0, 0, 0);
            acc[0][nt] = __builtin_amdgcn_mfma_f32_16x16x32_bf16(a0h, bl, acc[0][nt], 0, 0, 0);
            acc[0][nt] = __builtin_amdgcn_mfma_f32_16x16x32_bf16(a0l, bh, acc[0][nt], 0, 0, 0);
            acc[1][nt] = __builtin_amdgcn_mfma_f32_16x16x32_bf16(a1h, bh, acc[1][nt], 0, 0, 0);
            acc[1][nt] = __builtin_amdgcn_mfma_f32_16x16x32_bf16(a1h, bl, acc[1][nt], 0, 0, 0);
            acc[1][nt] = __builtin_amdgcn_mfma_f32_16x16x32_bf16(a1l, bh, acc[1][nt], 0, 0, 0);
        }
    }
    // ff1 epilogue -> E
#pragma unroll
    for (int m = 0; m < 2; ++m)
#pragma unroll
        for (int nt = 0; nt < 4; ++nt) {
            int ei = w * 64 + nt * 16 + col;
            float bv = b1[ei];
#pragma unroll
            for (int r = 0; r < 4; ++r) {
                int l = m * 16 + q * 4 + r;
                float v = geluf(acc[m][nt][r] + bv);
                unsigned short hh, ll;
                split2(v, hh, ll);
                int idx = (l * 256 + ei) ^ ((l & 7) << 3);
                Eh[idx] = hh; El[idx] = ll;
            }
        }
    __syncthreads();   // E complete; Z dead from here on
    f32x4 acc2[2][2];
#pragma unroll
    for (int m = 0; m < 2; ++m)
#pragma unroll
        for (int nt = 0; nt < 2; ++nt) acc2[m][nt] = (f32x4){0.f, 0.f, 0.f, 0.f};
#pragma unroll
    for (int ks = 0; ks < 8; ++ks) {
        int kb = ks * 32 + q * 8;
        int i0 = (col * 256 + kb) ^ ((col & 7) << 3);
        int i1 = ((16 + col) * 256 + kb) ^ ((col & 7) << 3);
        bfrag a0h = *(bfrag*)&Eh[i0], a0l = *(bfrag*)&El[i0];
        bfrag a1h = *(bfrag*)&Eh[i1], a1l = *(bfrag*)&El[i1];
#pragma unroll
        for (int nt = 0; nt < 2; ++nt) {
            int rt = w * 2 + nt;
            int off = ((rt * 8 + ks) * 64 + lane) * 8;
            bfrag bh = *(const bfrag*)&W2h[off];
            bfrag bl = *(const bfrag*)&W2l[off];
            acc2[0][nt] = __builtin_amdgcn_mfma_f32_16x16x32_bf16(a0h, bh, acc2[0][nt], 0, 0, 0);
            acc2[0][nt] = __builtin_amdgcn_mfma_f32_16x16x32_bf16(a0h, bl, acc2[0][nt], 0, 0, 0);
            acc2[0][nt] = __builtin_amdgcn_mfma_f32_16x16x32_bf16(a0l, bh, acc2[0][nt], 0, 0, 0);
            acc2[1][nt] = __builtin_amdgcn_mfma_f32_16x16x32_bf16(a1h, bh, acc2[1][nt], 0, 0, 0);
            acc2[1][nt] = __builtin_amdgcn_mfma_f32_16x16x32_bf16(a1h, bl, acc2[1][nt], 0, 0, 0);
            acc2[1][nt] = __builtin_amdgcn_mfma_f32_16x16x32_bf16(a1l, bh, acc2[1][nt], 0, 0, 0);
        }
    }
    // Rf overwrites Z region (dead after barrier above)
#pragma unroll
    for (int m = 0; m < 2; ++m)
#pragma unroll
        for (int nt = 0; nt < 2; ++nt) {
            int dout = w * 32 + nt * 16 + col;
            float bv = b2[dout];
#pragma unroll
            for (int r = 0; r < 4; ++r) {
                int l = m * 16 + q * 4 + r;
                Rf[l * 128 + dout] = acc2[m][nt][r] + bv;
            }
        }
    __syncthreads();
    size_t gb = l0 * Dm + (size_t)tid * 16;
#pragma unroll
    for (int i = 0; i < 4; ++i) {
        float4 r = *(float4*)&Rf[tid * 16 + i * 4];
        float4 o;
        o.x = hf[i * 4 + 0] + r.x; o.y = hf[i * 4 + 1] + r.y;
        o.z = hf[i * 4 + 2] + r.z; o.w = hf[i * 4 + 3] + r.w;
        *(float4*)&h[gb + i * 4] = o;
    }
}

// ---------------- head ----------------
__global__ void s4e_head(const float* __restrict__ h, const float* __restrict__ hw,
                         const float* __restrict__ hb, int* __restrict__ out) {
    __shared__ float logit[Bb][NCl];
    int tid = threadIdx.x;
    int b = tid >> 4, c = tid & 15;
    const float* hp = h + ((size_t)b * Ls + (Ls - 1)) * Dm;
    float acc = hb[c];
    for (int d = 0; d < Dm; ++d) acc = fmaf(hp[d], hw[c * Dm + d], acc);
    logit[b][c] = acc;
    __syncthreads();
    if (c == 0) {
        float best = logit[b][0]; int bi = 0;
#pragma unroll
        for (int k = 1; k < NCl; ++k) {
            float v = logit[b][k];
            if (v > best) { best = v; bi = k; }
        }
        out[b] = bi;
    }
}

extern "C" void kernel_launch(void* const* d_in, const int* in_sizes, int n_in,
                              void* d_out, int out_size, void* d_ws, size_t ws_size,
                              hipStream_t stream) {
    const float* x        = (const float*)d_in[0];
    const float* conv_w   = (const float*)d_in[1];
    const float* conv_b   = (const float*)d_in[2];
    const float* s4_ln_w  = (const float*)d_in[3];
    const float* s4_ln_b  = (const float*)d_in[4];
    const float* s4_logdt = (const float*)d_in[5];
    const float* s4_lAr   = (const float*)d_in[6];
    const float* s4_Aim   = (const float*)d_in[7];
    const float* s4_Cre   = (const float*)d_in[8];
    const float* s4_Cim   = (const float*)d_in[9];
    const float* s4_D     = (const float*)d_in[10];
    const float* s4_ow    = (const float*)d_in[11];
    const float* s4_ob    = (const float*)d_in[12];
    const float* ff_ln_w  = (const float*)d_in[13];
    const float* ff_ln_b  = (const float*)d_in[14];
    const float* ff_w1    = (const float*)d_in[15];
    const float* ff_b1    = (const float*)d_in[16];
    const float* ff_w2    = (const float*)d_in[17];
    const float* ff_b2    = (const float*)d_in[18];
    const float* head_w   = (const float*)d_in[19];
    const float* head_b   = (const float*)d_in[20];
    int* out = (int*)d_out;

    float* ws = (float*)d_ws;
    float* h  = ws;                                           // 64 MB
    float2* stats = (float2*)(ws + 16777216);                 // 1 MB
    float2* wv6 = (float2*)(ws + 17039360);                   // 6*4096 float2
    float2* wp6 = (float2*)(ws + 17088512);
    float2* Cc6 = (float2*)(ws + 17137664);
    unsigned short* wsp6 = (unsigned short*)(ws + 17186816);  // 6*196608 ushort
    unsigned short* acth = (unsigned short*)(ws + 33554432);  // 32 MB
    unsigned short* actl = (unsigned short*)(ws + 41943040);  // 32 MB
    float2* send  = (float2*)(ws + 50331648);                 // 33.5 MB (in-place prefix)

    s4e_conv<<<BL * 32 / 256, 256, 0, stream>>>(x, conv_w, conv_b, h);
    s4e_setup6<<<NBK, 128, 0, stream>>>(s4_logdt, s4_lAr, s4_Aim, s4_Cre, s4_Cim,
                                        wv6, wp6, Cc6);
    s4e_wsplit6<<<288, 256, 0, stream>>>(s4_ow, ff_w1, ff_w2, wsp6);
    for (int i = 0; i < NBK; ++i) {
        float2* wv = wv6 + i * (Nst * Dm);
        float2* wp = wp6 + i * (Nst * Dm);
        float2* Cc = Cc6 + i * (Nst * Dm);
        unsigned short* wsp = wsp6 + i * 196608;
        s4e_lnstat<<<BL / 64, 256, 0, stream>>>(h, stats);
        s4e_s1<<<2048, 256, 0, stream>>>(h, stats, s4_ln_w + i * Dm, s4_ln_b + i * Dm, wv, send);
        s4e_s2<<<256, 256, 0, stream>>>(wp, send);
        s4e_s3<<<2048, 256, 0, stream>>>(h, stats, s4_ln_w + i * Dm, s4_ln_b + i * Dm,
                                         wv, Cc, send, s4_D + i * Dm, acth, actl);
        s4e_outproj<<<BL / 32, 256, 0, stream>>>(acth, actl, wsp, s4_ob + i * Em, h);
        s4e_ffk<<<BL / 32, 256, 0, stream>>>(ff_ln_w + i * Dm, ff_ln_b + i * Dm, wsp,
                                             ff_b1 + i * Em, ff_b2 + i * Dm, h);
    }
    s4e_head<<<1, 256, 0, stream>>>(h, head_w, head_b, out);
}

// Round 14
// 1967.866 us; speedup vs baseline: 1.0943x; 1.0943x over previous
//
#include <hip/hip_runtime.h>
#include <math.h>

#define Bb 16
#define Ls 8192
#define Dm 128
#define NBK 6
#define Nst 32
#define NCl 16
#define Em 256
#define LC 128
#define NCH 64
#define BL (Bb*Ls)

typedef __attribute__((ext_vector_type(8))) short bfrag;   // 8 bf16 (4 VGPRs)
typedef __attribute__((ext_vector_type(4))) float f32x4;

// fast gelu (tanh-approx form, via exp2/rcp; branch-free)
__device__ __forceinline__ float geluf(float x) {
    float t = x * x;
    float g = x * fmaf(0.102952207f, t, 2.30234547f);   // 2u*log2(e)
    float e = exp2f(-g);
    return x * __builtin_amdgcn_rcpf(1.f + e);
}
__device__ __forceinline__ float sigmf(float x) {
    return __builtin_amdgcn_rcpf(1.f + exp2f(-1.44269504f * x));
}

__device__ __forceinline__ unsigned short bf16r(float x) {
    unsigned u = __float_as_uint(x);
    return (unsigned short)((u + 0x7FFFu + ((u >> 16) & 1u)) >> 16);
}
__device__ __forceinline__ void split2(float x, unsigned short& h, unsigned short& l) {
    h = bf16r(x);
    float hf = __uint_as_float(((unsigned)h) << 16);
    l = bf16r(x - hf);
}

// ---------------- conv: h[b,l,d] (token-major) + layer-0 LN stats ----------------
__global__ void s4e_conv(const float* __restrict__ x, const float* __restrict__ cw,
                         const float* __restrict__ cb, float* __restrict__ h,
                         float2* __restrict__ stats) {
    int tid = blockIdx.x * 256 + threadIdx.x;     // B*L*32
    int d4 = tid & 31;
    int t = tid >> 5;
    int l = t & (Ls - 1);
    int b = t >> 13;
    const float* xb = x + (size_t)b * Ls;
    float xs[5];
#pragma unroll
    for (int k = 0; k < 5; ++k) {
        int p = l + k - 2;
        xs[k] = (p >= 0 && p < Ls) ? xb[p] : 0.f;
    }
    float4 acc;
    float* ap = &acc.x;
#pragma unroll
    for (int j = 0; j < 4; ++j) {
        int d = d4 * 4 + j;
        float a = cb[d];
#pragma unroll
        for (int k = 0; k < 5; ++k) a = fmaf(cw[d * 5 + k], xs[k], a);
        ap[j] = a;
    }
    *(float4*)&h[(size_t)t * Dm + d4 * 4] = acc;
    // LN stats over the 128 d of this token (32 lanes per token, contiguous)
    float s = acc.x + acc.y + acc.z + acc.w;
    float q = acc.x * acc.x + acc.y * acc.y + acc.z * acc.z + acc.w * acc.w;
    s += __shfl_xor(s, 1);  q += __shfl_xor(q, 1);
    s += __shfl_xor(s, 2);  q += __shfl_xor(q, 2);
    s += __shfl_xor(s, 4);  q += __shfl_xor(q, 4);
    s += __shfl_xor(s, 8);  q += __shfl_xor(q, 8);
    s += __shfl_xor(s, 16); q += __shfl_xor(q, 16);
    if (d4 == 0) {
        float mu = s * (1.f / Dm);
        float rs = rsqrtf(q * (1.f / Dm) - mu * mu + 1e-5f);
        stats[t] = make_float2(mu, rs);
    }
}

// ---------------- S4 params for ALL layers: [n][d], wp = w^LC, Cc pre-doubled ----------------
__global__ void s4e_setup6(const float* __restrict__ log_dt, const float* __restrict__ lAr,
                           const float* __restrict__ Aim, const float* __restrict__ Cre,
                           const float* __restrict__ Cim, float2* __restrict__ wv6,
                           float2* __restrict__ wp6, float2* __restrict__ Cc6) {
    int i = blockIdx.x;          // layer
    int d = threadIdx.x;
    const float* ld  = log_dt + i * Dm;
    const float* la  = lAr + i * Dm * Nst;
    const float* ai  = Aim + i * Dm * Nst;
    const float* cre = Cre + i * Dm * Nst;
    const float* cim = Cim + i * Dm * Nst;
    float2* wv = wv6 + i * (Nst * Dm);
    float2* wp = wp6 + i * (Nst * Dm);
    float2* Cc = Cc6 + i * (Nst * Dm);
    float dt = expf(ld[d]);
    for (int n = 0; n < Nst; ++n) {
        int id = d * Nst + n;
        float Ar = -expf(la[id]);
        float Ai = ai[id];
        float xr = dt * Ar, xi = dt * Ai;
        float er = expf(xr);
        float wr = er * cosf(xi), wi = er * sinf(xi);
        wv[n * Dm + d] = make_float2(wr, wi);
        float den = Ar * Ar + Ai * Ai;
        float inv = 1.f / den;
        float fr = ((wr - 1.f) * Ar + wi * Ai) * inv;
        float fi = (wi * Ar - (wr - 1.f) * Ai) * inv;
        Cc[n * Dm + d] = make_float2(2.f * (cre[id] * fr - cim[id] * fi),
                                     2.f * (cre[id] * fi + cim[id] * fr));
        float pr = wr, pi = wi;
#pragma unroll
        for (int sq = 0; sq < 7; ++sq) {     // w^128 = w^LC
            float nr = pr * pr - pi * pi;
            float ni = 2.f * pr * pi;
            pr = nr; pi = ni;
        }
        wp[n * Dm + d] = make_float2(pr, pi);
    }
}

// ---------------- weight split + MFMA-fragment pack, ALL layers ----------------
// packed[((rt*KT + kt)*64 + lane)*8 + j] = W[rt*16 + (lane&15)][kt*32 + (lane>>4)*8 + j]
__global__ void s4e_wsplit6(const float* __restrict__ ow, const float* __restrict__ w1,
                            const float* __restrict__ w2, unsigned short* __restrict__ base0) {
    int idx = blockIdx.x * 256 + threadIdx.x;   // 6 layers * 12288 groups
    int layer = idx / 12288;
    int r = idx - layer * 12288;
    int mat = r >> 12;
    int g = r & 4095;
    int lane = g & 63;
    int fid = g >> 6;
    int col = lane & 15, q = lane >> 4;
    unsigned short* base = base0 + layer * 196608;
    const float* src;
    unsigned short *dh, *dl_;
    int rt, kt, K;
    if (mat == 0)      { src = ow + layer * 32768; K = 128; dh = base;          dl_ = base + 32768;  rt = fid >> 2; kt = fid & 3; }
    else if (mat == 1) { src = w1 + layer * 32768; K = 128; dh = base + 65536;  dl_ = base + 98304;  rt = fid >> 2; kt = fid & 3; }
    else               { src = w2 + layer * 32768; K = 256; dh = base + 131072; dl_ = base + 163840; rt = fid >> 3; kt = fid & 7; }
    int row = rt * 16 + col;
    int k0 = kt * 32 + q * 8;
    const float* sp = src + row * K + k0;
    bfrag vh, vl;
#pragma unroll
    for (int j = 0; j < 8; ++j) {
        unsigned short hh, ll;
        split2(sp[j], hh, ll);
        vh[j] = (short)hh; vl[j] = (short)ll;
    }
    *(bfrag*)&dh[g * 8] = vh;
    *(bfrag*)&dl_[g * 8] = vl;
}

// ---------------- S1: end states, inline LN, 4-way mode split (8 modes/thread) ----------------
__global__ __launch_bounds__(256) void s4e_s1(const float* __restrict__ h,
        const float2* __restrict__ stats, const float* __restrict__ lnw,
        const float* __restrict__ lnb, const float2* __restrict__ wv,
        float2* __restrict__ send) {
    __shared__ float2 stl[LC];
    int tid = threadIdx.x;
    int blk = blockIdx.x;            // (b*NCH + c)*2 + half
    int half = blk & 1;
    int chunk = blk >> 1;
    int c = chunk & (NCH - 1);
    int b = chunk >> 6;
    int dl = tid & 15;
    int m  = (tid >> 4) & 3;
    int dq = tid >> 6;
    int d  = half * 64 + dq * 16 + dl;
    int n0 = m * 8;
    if (tid < LC) stl[tid] = stats[(size_t)b * Ls + c * LC + tid];
    float wr[8], wi[8], sr[8], si[8];
#pragma unroll
    for (int k = 0; k < 8; ++k) {
        float2 t = wv[(n0 + k) * Dm + d];
        wr[k] = t.x; wi[k] = t.y; sr[k] = 0.f; si[k] = 0.f;
    }
    float wd = lnw[d], bd = lnb[d];
    const float* hp = h + ((size_t)b * Ls + c * LC) * Dm + d;
    __syncthreads();
#pragma unroll 1
    for (int j = 0; j < LC; j += 4) {
        float hv[4];
#pragma unroll
        for (int u = 0; u < 4; ++u) hv[u] = hp[(size_t)(j + u) * Dm];
        float zv[4];
#pragma unroll
        for (int u = 0; u < 4; ++u) {
            float2 sj = stl[j + u];
            zv[u] = (hv[u] - sj.x) * sj.y * wd + bd;
        }
#pragma unroll
        for (int u = 0; u < 4; ++u) {
            float z = zv[u];
#pragma unroll
            for (int k = 0; k < 8; ++k) {
                float t = fmaf(-wi[k], si[k], z);
                float nr = fmaf(wr[k], sr[k], t);
                float ni = fmaf(wi[k], sr[k], wr[k] * si[k]);
                sr[k] = nr; si[k] = ni;
            }
        }
    }
    float2* o = send + ((size_t)(b * NCH + c) * Nst + n0) * Dm + d;
#pragma unroll
    for (int k = 0; k < 8; ++k) o[k * Dm] = make_float2(sr[k], si[k]);
}

// ---------------- S2: in-place cross-chunk prefix ----------------
__global__ void s4e_s2(const float2* __restrict__ wp, float2* __restrict__ s) {
    int tid = blockIdx.x * 256 + threadIdx.x;   // B*Nst*Dm = 65536
    int d = tid & 127;
    int n = (tid >> 7) & 31;
    int b = tid >> 12;
    float2 W = wp[n * Dm + d];
    float Sr = 0.f, Si = 0.f;
    size_t base = ((size_t)(b * NCH) * Nst + n) * Dm + d;
    size_t cs = (size_t)Nst * Dm;
    for (int c0 = 0; c0 < NCH; c0 += 8) {
        float2 E[8];
#pragma unroll
        for (int k = 0; k < 8; ++k) E[k] = s[base + (size_t)(c0 + k) * cs];
#pragma unroll
        for (int k = 0; k < 8; ++k) {
            float2 o = make_float2(Sr, Si);
            float nr = fmaf(W.x, Sr, fmaf(-W.y, Si, E[k].x));
            float ni = fmaf(W.x, Si, fmaf(W.y, Sr, E[k].y));
            Sr = nr; Si = ni;
            s[base + (size_t)(c0 + k) * cs] = o;
        }
    }
}

// ---------------- S3: re-scan, inline LN, 2-way mode split (16 modes/thread) ----------------
__global__ __launch_bounds__(256) void s4e_s3(const float* __restrict__ h,
        const float2* __restrict__ stats, const float* __restrict__ lnw,
        const float* __restrict__ lnb, const float2* __restrict__ wv,
        const float2* __restrict__ Cc, const float2* __restrict__ sinit,
        const float* __restrict__ Dsk,
        unsigned short* __restrict__ acth, unsigned short* __restrict__ actl) {
    __shared__ float2 stl[LC];
    int tid = threadIdx.x;
    int blk = blockIdx.x;            // b*NCH + c
    int c = blk & (NCH - 1);
    int b = blk >> 6;
    int dl = tid & 31;
    int m  = (tid >> 5) & 1;
    int dh = tid >> 6;
    int d  = dh * 32 + dl;
    int n0 = m * 16;
    if (tid < LC) stl[tid] = stats[(size_t)b * Ls + c * LC + tid];
    float wr[16], wi[16], cr[16], ci[16], sr[16], si[16];
    const float2* s0 = sinit + ((size_t)(b * NCH + c) * Nst + n0) * Dm + d;
#pragma unroll
    for (int k = 0; k < 16; ++k) {
        float2 t = wv[(n0 + k) * Dm + d];  wr[k] = t.x; wi[k] = t.y;
        float2 cc = Cc[(n0 + k) * Dm + d]; cr[k] = cc.x; ci[k] = cc.y;
        float2 ss = s0[k * Dm];            sr[k] = ss.x; si[k] = ss.y;
    }
    float wd = lnw[d], bd = lnb[d];
    float Dv = Dsk[d];
    size_t ib = ((size_t)b * Ls + c * LC) * Dm + d;
    __syncthreads();
#pragma unroll 1
    for (int j = 0; j < LC; j += 4) {
        float hv[4];
#pragma unroll
        for (int u = 0; u < 4; ++u) hv[u] = h[ib + (size_t)(j + u) * Dm];
        float zv[4];
#pragma unroll
        for (int u = 0; u < 4; ++u) {
            float2 sj = stl[j + u];
            zv[u] = (hv[u] - sj.x) * sj.y * wd + bd;
        }
#pragma unroll
        for (int u = 0; u < 4; ++u) {
            float z = zv[u];
            float acc = 0.f;
#pragma unroll
            for (int k = 0; k < 16; ++k) {
                float t = fmaf(-wi[k], si[k], z);
                float nr = fmaf(wr[k], sr[k], t);
                float ni = fmaf(wi[k], sr[k], wr[k] * si[k]);
                sr[k] = nr; si[k] = ni;
                acc = fmaf(cr[k], nr, acc);
                acc = fmaf(-ci[k], ni, acc);
            }
            acc += __shfl_xor(acc, 32);
            if (m == 0) {
                float av = geluf(fmaf(Dv, z, acc));
                unsigned short hh, ll;
                split2(av, hh, ll);
                acth[ib + (size_t)(j + u) * Dm] = hh;
                actl[ib + (size_t)(j + u) * Dm] = ll;
            }
        }
    }
}

// ---------------- outproj GEMM (bf16x3 MFMA, packed weights) + GLU ----------------
__global__ __launch_bounds__(256) void s4e_outproj(const unsigned short* __restrict__ acth,
        const unsigned short* __restrict__ actl, const unsigned short* __restrict__ wsp,
        const float* __restrict__ bias, float* __restrict__ h) {
    __shared__ __align__(16) unsigned short smem[8192];   // Ah 8K | Al 8K ; Rf aliases 16K
    unsigned short* Ah = smem;
    unsigned short* Al = smem + 4096;
    float* Rf = (float*)smem;
    const unsigned short* Whi = wsp;
    const unsigned short* Wlo = wsp + 32768;
    size_t l0 = (size_t)blockIdx.x * 32;
    int tid = threadIdx.x;
    {
        const unsigned short* gh = acth + l0 * Dm;
        const unsigned short* gl = actl + l0 * Dm;
        for (int i = tid * 8; i < 32 * 128; i += 2048) {
            int r = i >> 7;
            int di = i ^ ((r & 7) << 3);
            *(bfrag*)&Ah[di] = *(const bfrag*)&gh[i];
            *(bfrag*)&Al[di] = *(const bfrag*)&gl[i];
        }
    }
    __syncthreads();
    int w = tid >> 6, lane = tid & 63;
    int col = lane & 15, q = lane >> 4;
    f32x4 acc[2][4];
#pragma unroll
    for (int m = 0; m < 2; ++m)
#pragma unroll
        for (int nt = 0; nt < 4; ++nt) acc[m][nt] = (f32x4){0.f, 0.f, 0.f, 0.f};
#pragma unroll
    for (int ks = 0; ks < 4; ++ks) {
        int kb = ks * 32 + q * 8;
        int i0 = (col * 128 + kb) ^ ((col & 7) << 3);
        int i1 = ((16 + col) * 128 + kb) ^ ((col & 7) << 3);
        bfrag a0h = *(bfrag*)&Ah[i0], a0l = *(bfrag*)&Al[i0];
        bfrag a1h = *(bfrag*)&Ah[i1], a1l = *(bfrag*)&Al[i1];
#pragma unroll
        for (int nt = 0; nt < 4; ++nt) {
            int rt = (nt < 2) ? (w * 2 + nt) : (8 + w * 2 + (nt - 2));
            int off = ((rt * 4 + ks) * 64 + lane) * 8;
            bfrag bh = *(const bfrag*)&Whi[off];
            bfrag bl = *(const bfrag*)&Wlo[off];
            acc[0][nt] = __builtin_amdgcn_mfma_f32_16x16x32_bf16(a0h, bh, acc[0][nt], 0, 0, 0);
            acc[0][nt] = __builtin_amdgcn_mfma_f32_16x16x32_bf16(a0h, bl, acc[0][nt], 0, 0, 0);
            acc[0][nt] = __builtin_amdgcn_mfma_f32_16x16x32_bf16(a0l, bh, acc[0][nt], 0, 0, 0);
            acc[1][nt] = __builtin_amdgcn_mfma_f32_16x16x32_bf16(a1h, bh, acc[1][nt], 0, 0, 0);
            acc[1][nt] = __builtin_amdgcn_mfma_f32_16x16x32_bf16(a1h, bl, acc[1][nt], 0, 0, 0);
            acc[1][nt] = __builtin_amdgcn_mfma_f32_16x16x32_bf16(a1l, bh, acc[1][nt], 0, 0, 0);
        }
    }
    __syncthreads();   // all Ah/Al reads done before Rf overwrite
#pragma unroll
    for (int m = 0; m < 2; ++m)
#pragma unroll
        for (int nt = 0; nt < 2; ++nt) {
            int dout = w * 32 + nt * 16 + col;
            float ba = bias[dout], bg = bias[dout + 128];
#pragma unroll
            for (int r = 0; r < 4; ++r) {
                int l = m * 16 + q * 4 + r;
                float a = acc[m][nt][r] + ba;
                float g = acc[m][nt + 2][r] + bg;
                Rf[l * 128 + dout] = a * sigmf(g);
            }
        }
    __syncthreads();
    size_t gb = l0 * Dm + (size_t)tid * 16;
#pragma unroll
    for (int i = 0; i < 4; ++i) {
        float4 r = *(float4*)&Rf[tid * 16 + i * 4];
        float4 hv = *(float4*)&h[gb + i * 4];
        hv.x += r.x; hv.y += r.y; hv.z += r.z; hv.w += r.w;
        *(float4*)&h[gb + i * 4] = hv;
    }
}

// ---------------- fused LN + FF GEMM (bf16x3 MFMA, packed weights) + next-layer stats ----------------
__global__ __launch_bounds__(256) void s4e_ffk(const float* __restrict__ lnw,
        const float* __restrict__ lnb, const unsigned short* __restrict__ wsp,
        const float* __restrict__ b1, const float* __restrict__ b2, float* __restrict__ h,
        float2* __restrict__ stats) {
    __shared__ __align__(16) unsigned short smem[24576]; // Zh 8K|Zl 8K|Eh 16K|El 16K (bytes)
    unsigned short* Zh = smem;
    unsigned short* Zl = smem + 4096;
    unsigned short* Eh = smem + 8192;
    unsigned short* El = smem + 16384;
    float* Rf = (float*)smem;                 // aliases Zh+Zl (16 KB)
    const unsigned short* W1h = wsp + 65536;
    const unsigned short* W1l = wsp + 98304;
    const unsigned short* W2h = wsp + 131072;
    const unsigned short* W2l = wsp + 163840;
    size_t l0 = (size_t)blockIdx.x * 32;
    int tid = threadIdx.x;
    // ---- fused LN
    float hf[16];
    float s = 0.f, qq = 0.f;
    {
        const float* hp = h + l0 * Dm + (size_t)tid * 16;
#pragma unroll
        for (int i = 0; i < 4; ++i) {
            float4 v = *(const float4*)(hp + i * 4);
            hf[i * 4 + 0] = v.x; hf[i * 4 + 1] = v.y;
            hf[i * 4 + 2] = v.z; hf[i * 4 + 3] = v.w;
            s += v.x + v.y + v.z + v.w;
            qq += v.x * v.x + v.y * v.y + v.z * v.z + v.w * v.w;
        }
    }
    s  += __shfl_xor(s, 1);  s += __shfl_xor(s, 2);  s += __shfl_xor(s, 4);
    qq += __shfl_xor(qq, 1); qq += __shfl_xor(qq, 2); qq += __shfl_xor(qq, 4);
    float mu = s * (1.f / Dm);
    float rs = rsqrtf(qq * (1.f / Dm) - mu * mu + 1e-5f);
    int tok = tid >> 3, dc = (tid & 7) * 16;
#pragma unroll
    for (int g = 0; g < 2; ++g) {
        bfrag vh, vl;
#pragma unroll
        for (int k = 0; k < 8; ++k) {
            int d = dc + g * 8 + k;
            float v = (hf[g * 8 + k] - mu) * rs * lnw[d] + lnb[d];
            unsigned short hh, ll;
            split2(v, hh, ll);
            vh[k] = (short)hh; vl[k] = (short)ll;
        }
        int idx = (tok * 128 + dc + g * 8) ^ ((tok & 7) << 3);
        *(bfrag*)&Zh[idx] = vh;
        *(bfrag*)&Zl[idx] = vl;
    }
    __syncthreads();
    int w = tid >> 6, lane = tid & 63;
    int col = lane & 15, q = lane >> 4;
    f32x4 acc[2][4];
#pragma unroll
    for (int m = 0; m < 2; ++m)
#pragma unroll
        for (int nt = 0; nt < 4; ++nt) acc[m][nt] = (f32x4){0.f, 0.f, 0.f, 0.f};
#pragma unroll
    for (int ks = 0; ks < 4; ++ks) {
        int kb = ks * 32 + q * 8;
        int i0 = (col * 128 + kb) ^ ((col & 7) << 3);
        int i1 = ((16 + col) * 128 + kb) ^ ((col & 7) << 3);
        bfrag a0h = *(bfrag*)&Zh[i0], a0l = *(bfrag*)&Zl[i0];
        bfrag a1h = *(bfrag*)&Zh[i1], a1l = *(bfrag*)&Zl[i1];
#pragma unroll
        for (int nt = 0; nt < 4; ++nt) {
            int rt = w * 4 + nt;
            int off = ((rt * 4 + ks) * 64 + lane) * 8;
            bfrag bh = *(const bfrag*)&W1h[off];
            bfrag bl = *(const bfrag*)&W1l[off];
            acc[0][nt] = __builtin_amdgcn_mfma_f32_16x16x32_bf16(a0h, bh, acc[0][nt], 0, 0, 0);
            acc[0][nt] = __builtin_amdgcn_mfma_f32_16x16x32_bf16(a0h, bl, acc[0][nt], 0, 0, 0);
            acc[0][nt] = __builtin_amdgcn_mfma_f32_16x16x32_bf16(a0l, bh, acc[0][nt], 0, 0, 0);
            acc[1][nt] = __builtin_amdgcn_mfma_f32_16x16x32_bf16(a1h, bh, acc[1][nt], 0, 0, 0);
            acc[1][nt] = __builtin_amdgcn_mfma_f32_16x16x32_bf16(a1h, bl, acc[1][nt], 0, 0, 0);
            acc[1][nt] = __builtin_amdgcn_mfma_f32_16x16x32_bf16(a1l, bh, acc[1][nt], 0, 0, 0);
        }
    }
    // ff1 epilogue -> E
#pragma unroll
    for (int m = 0; m < 2; ++m)
#pragma unroll
        for (int nt = 0; nt < 4; ++nt) {
            int ei = w * 64 + nt * 16 + col;
            float bv = b1[ei];
#pragma unroll
            for (int r = 0; r < 4; ++r) {
                int l = m * 16 + q * 4 + r;
                float v = geluf(acc[m][nt][r] + bv);
                unsigned short hh, ll;
                split2(v, hh, ll);
                int idx = (l * 256 + ei) ^ ((l & 7) << 3);
                Eh[idx] = hh; El[idx] = ll;
            }
        }
    __syncthreads();   // E complete; Z dead from here on
    f32x4 acc2[2][2];
#pragma unroll
    for (int m = 0; m < 2; ++m)
#pragma unroll
        for (int nt = 0; nt < 2; ++nt) acc2[m][nt] = (f32x4){0.f, 0.f, 0.f, 0.f};
#pragma unroll
    for (int ks = 0; ks < 8; ++ks) {
        int kb = ks * 32 + q * 8;
        int i0 = (col * 256 + kb) ^ ((col & 7) << 3);
        int i1 = ((16 + col) * 256 + kb) ^ ((col & 7) << 3);
        bfrag a0h = *(bfrag*)&Eh[i0], a0l = *(bfrag*)&El[i0];
        bfrag a1h = *(bfrag*)&Eh[i1], a1l = *(bfrag*)&El[i1];
#pragma unroll
        for (int nt = 0; nt < 2; ++nt) {
            int rt = w * 2 + nt;
            int off = ((rt * 8 + ks) * 64 + lane) * 8;
            bfrag bh = *(const bfrag*)&W2h[off];
            bfrag bl = *(const bfrag*)&W2l[off];
            acc2[0][nt] = __builtin_amdgcn_mfma_f32_16x16x32_bf16(a0h, bh, acc2[0][nt], 0, 0, 0);
            acc2[0][nt] = __builtin_amdgcn_mfma_f32_16x16x32_bf16(a0h, bl, acc2[0][nt], 0, 0, 0);
            acc2[0][nt] = __builtin_amdgcn_mfma_f32_16x16x32_bf16(a0l, bh, acc2[0][nt], 0, 0, 0);
            acc2[1][nt] = __builtin_amdgcn_mfma_f32_16x16x32_bf16(a1h, bh, acc2[1][nt], 0, 0, 0);
            acc2[1][nt] = __builtin_amdgcn_mfma_f32_16x16x32_bf16(a1h, bl, acc2[1][nt], 0, 0, 0);
            acc2[1][nt] = __builtin_amdgcn_mfma_f32_16x16x32_bf16(a1l, bh, acc2[1][nt], 0, 0, 0);
        }
    }
    // Rf overwrites Z region (dead after barrier above)
#pragma unroll
    for (int m = 0; m < 2; ++m)
#pragma unroll
        for (int nt = 0; nt < 2; ++nt) {
            int dout = w * 32 + nt * 16 + col;
            float bv = b2[dout];
#pragma unroll
            for (int r = 0; r < 4; ++r) {
                int l = m * 16 + q * 4 + r;
                Rf[l * 128 + dout] = acc2[m][nt][r] + bv;
            }
        }
    __syncthreads();
    size_t gb = l0 * Dm + (size_t)tid * 16;
    float s2_ = 0.f, q2_ = 0.f;
#pragma unroll
    for (int i = 0; i < 4; ++i) {
        float4 r = *(float4*)&Rf[tid * 16 + i * 4];
        float4 o;
        o.x = hf[i * 4 + 0] + r.x; o.y = hf[i * 4 + 1] + r.y;
        o.z = hf[i * 4 + 2] + r.z; o.w = hf[i * 4 + 3] + r.w;
        *(float4*)&h[gb + i * 4] = o;
        s2_ += o.x + o.y + o.z + o.w;
        q2_ += o.x * o.x + o.y * o.y + o.z * o.z + o.w * o.w;
    }
    // next-layer LN stats (8 lanes per token, contiguous)
    s2_ += __shfl_xor(s2_, 1); q2_ += __shfl_xor(q2_, 1);
    s2_ += __shfl_xor(s2_, 2); q2_ += __shfl_xor(q2_, 2);
    s2_ += __shfl_xor(s2_, 4); q2_ += __shfl_xor(q2_, 4);
    if ((tid & 7) == 0) {
        float mu2 = s2_ * (1.f / Dm);
        float rs2 = rsqrtf(q2_ * (1.f / Dm) - mu2 * mu2 + 1e-5f);
        stats[l0 + (tid >> 3)] = make_float2(mu2, rs2);
    }
}

// ---------------- head ----------------
__global__ void s4e_head(const float* __restrict__ h, const float* __restrict__ hw,
                         const float* __restrict__ hb, int* __restrict__ out) {
    __shared__ float logit[Bb][NCl];
    int tid = threadIdx.x;
    int b = tid >> 4, c = tid & 15;
    const float* hp = h + ((size_t)b * Ls + (Ls - 1)) * Dm;
    float acc = hb[c];
    for (int d = 0; d < Dm; ++d) acc = fmaf(hp[d], hw[c * Dm + d], acc);
    logit[b][c] = acc;
    __syncthreads();
    if (c == 0) {
        float best = logit[b][0]; int bi = 0;
#pragma unroll
        for (int k = 1; k < NCl; ++k) {
            float v = logit[b][k];
            if (v > best) { best = v; bi = k; }
        }
        out[b] = bi;
    }
}

extern "C" void kernel_launch(void* const* d_in, const int* in_sizes, int n_in,
                              void* d_out, int out_size, void* d_ws, size_t ws_size,
                              hipStream_t stream) {
    const float* x        = (const float*)d_in[0];
    const float* conv_w   = (const float*)d_in[1];
    const float* conv_b   = (const float*)d_in[2];
    const float* s4_ln_w  = (const float*)d_in[3];
    const float* s4_ln_b  = (const float*)d_in[4];
    const float* s4_logdt = (const float*)d_in[5];
    const float* s4_lAr   = (const float*)d_in[6];
    const float* s4_Aim   = (const float*)d_in[7];
    const float* s4_Cre   = (const float*)d_in[8];
    const float* s4_Cim   = (const float*)d_in[9];
    const float* s4_D     = (const float*)d_in[10];
    const float* s4_ow    = (const float*)d_in[11];
    const float* s4_ob    = (const float*)d_in[12];
    const float* ff_ln_w  = (const float*)d_in[13];
    const float* ff_ln_b  = (const float*)d_in[14];
    const float* ff_w1    = (const float*)d_in[15];
    const float* ff_b1    = (const float*)d_in[16];
    const float* ff_w2    = (const float*)d_in[17];
    const float* ff_b2    = (const float*)d_in[18];
    const float* head_w   = (const float*)d_in[19];
    const float* head_b   = (const float*)d_in[20];
    int* out = (int*)d_out;

    float* ws = (float*)d_ws;
    float* h  = ws;                                           // 64 MB
    float2* stats = (float2*)(ws + 16777216);                 // 1 MB
    float2* wv6 = (float2*)(ws + 17039360);                   // 6*4096 float2
    float2* wp6 = (float2*)(ws + 17088512);
    float2* Cc6 = (float2*)(ws + 17137664);
    unsigned short* wsp6 = (unsigned short*)(ws + 17186816);  // 6*196608 ushort
    unsigned short* acth = (unsigned short*)(ws + 33554432);  // 32 MB
    unsigned short* actl = (unsigned short*)(ws + 41943040);  // 32 MB
    float2* send  = (float2*)(ws + 50331648);                 // 33.5 MB (in-place prefix)

    s4e_conv<<<BL * 32 / 256, 256, 0, stream>>>(x, conv_w, conv_b, h, stats);
    s4e_setup6<<<NBK, 128, 0, stream>>>(s4_logdt, s4_lAr, s4_Aim, s4_Cre, s4_Cim,
                                        wv6, wp6, Cc6);
    s4e_wsplit6<<<288, 256, 0, stream>>>(s4_ow, ff_w1, ff_w2, wsp6);
    for (int i = 0; i < NBK; ++i) {
        float2* wv = wv6 + i * (Nst * Dm);
        float2* wp = wp6 + i * (Nst * Dm);
        float2* Cc = Cc6 + i * (Nst * Dm);
        unsigned short* wsp = wsp6 + i * 196608;
        s4e_s1<<<2048, 256, 0, stream>>>(h, stats, s4_ln_w + i * Dm, s4_ln_b + i * Dm, wv, send);
        s4e_s2<<<256, 256, 0, stream>>>(wp, send);
        s4e_s3<<<1024, 256, 0, stream>>>(h, stats, s4_ln_w + i * Dm, s4_ln_b + i * Dm,
                                         wv, Cc, send, s4_D + i * Dm, acth, actl);
        s4e_outproj<<<BL / 32, 256, 0, stream>>>(acth, actl, wsp, s4_ob + i * Em, h);
        s4e_ffk<<<BL / 32, 256, 0, stream>>>(ff_ln_w + i * Dm, ff_ln_b + i * Dm, wsp,
                                             ff_b1 + i * Em, ff_b2 + i * Dm, h, stats);
    }
    s4e_head<<<1, 256, 0, stream>>>(h, head_w, head_b, out);
}